// Round 12
// baseline (303.760 us; speedup 1.0000x reference)
//
#include <hip/hip_runtime.h>
#include <hip/hip_bf16.h>
#include <stdint.h>

#define B_ 8
#define S_ 2048
#define E_ 768

typedef __attribute__((ext_vector_type(4))) float f32x4;
typedef __attribute__((ext_vector_type(8))) short bf16x8;

// GEMM core: BM=BN=128, BK=32, 256 thr (4 waves 2Mx2N, 64x64/wave),
// 3 LDS buffers x (A 8KB + B 8KB) = 48 KB/block -> 3 blocks/CU resident,
// lead-2 prefetch with counted vmcnt(4) (never 0 mid-loop).
// GEMM grids are 1-D, XCD-chunked (T1; bijective, all grids %8==0).

__device__ __forceinline__ unsigned pk2bf(float x, float y) {
  unsigned r;
  asm("v_cvt_pk_bf16_f32 %0, %1, %2" : "=v"(r) : "v"(x), "v"(y));
  return r;
}

__device__ __forceinline__ void gll16(const void* g, void* l) {
  __builtin_amdgcn_global_load_lds((const __attribute__((address_space(1))) void*)g,
                                   (__attribute__((address_space(3))) void*)l, 16, 0, 0);
}

// Swizzle (64B rows = 32 bf16): chunk' = chunk ^ ((row>>1)&3) -> 2-way (free).
// LDS dest linear; global SOURCE pre-swizzled (involution, rule #21).
__device__ __forceinline__ void gemm128(const char* __restrict__ Ab,
                                        const char* __restrict__ Bb,
                                        int ldA, int ldB, int NT,
                                        unsigned short* As, unsigned short* Bs,
                                        int tid, int wm, int wn, int lane,
                                        f32x4 (&acc)[4][4]) {
  unsigned sA[2], sB[2], lin2[2];
#pragma unroll
  for (int i = 0; i < 2; ++i) {
    const unsigned lin = (unsigned)i * 4096u + (unsigned)tid * 16u;
    const unsigned row = lin >> 6, ch = (lin >> 4) & 3u;
    const unsigned sw = (ch ^ ((row >> 1) & 3u)) << 4;
    sA[i] = row * (unsigned)ldA + sw;
    sB[i] = row * (unsigned)ldB + sw;
    lin2[i] = lin;
  }
  unsigned aoff[4], boff[4];
#pragma unroll
  for (int m = 0; m < 4; ++m) {
    unsigned row = (unsigned)(wm * 64 + m * 16 + (lane & 15));
    aoff[m] = row * 64 + ((((unsigned)lane >> 4) ^ ((row >> 1) & 3u)) << 4);
    row = (unsigned)(wn * 64 + m * 16 + (lane & 15));
    boff[m] = row * 64 + ((((unsigned)lane >> 4) ^ ((row >> 1) & 3u)) << 4);
  }
  // prologue: stage tiles 0,1 into buffers 0,1; wait only tile 0 (vmcnt(4)).
#pragma unroll
  for (int i = 0; i < 2; ++i) {
    gll16(Ab + sA[i], (char*)As + lin2[i]);
    gll16(Bb + sB[i], (char*)Bs + lin2[i]);
  }
#pragma unroll
  for (int i = 0; i < 2; ++i) {
    gll16(Ab + sA[i] + 64, (char*)As + 8192 + lin2[i]);
    gll16(Bb + sB[i] + 64, (char*)Bs + 8192 + lin2[i]);
  }
  asm volatile("s_waitcnt vmcnt(4)" ::: "memory");
  __builtin_amdgcn_s_barrier();
  __builtin_amdgcn_sched_barrier(0);
  for (int kt = 0; kt < NT; ++kt) {
    const int bc = kt % 3;
    const char* Ac = (const char*)As + bc * 8192;
    const char* Bc = (const char*)Bs + bc * 8192;
    if (kt + 2 < NT) {
      const int bn = (kt + 2) % 3;
      const size_t ko = (size_t)(kt + 2) * 64;
#pragma unroll
      for (int i = 0; i < 2; ++i) {
        gll16(Ab + sA[i] + ko, (char*)As + bn * 8192 + lin2[i]);
        gll16(Bb + sB[i] + ko, (char*)Bs + bn * 8192 + lin2[i]);
      }
    }
    bf16x8 af[4], bf[4];
#pragma unroll
    for (int m = 0; m < 4; ++m) af[m] = *reinterpret_cast<const bf16x8*>(Ac + aoff[m]);
#pragma unroll
    for (int n = 0; n < 4; ++n) bf[n] = *reinterpret_cast<const bf16x8*>(Bc + boff[n]);
    asm volatile("s_waitcnt lgkmcnt(0)" ::: "memory");
    __builtin_amdgcn_sched_barrier(0);
    __builtin_amdgcn_s_setprio(1);
#pragma unroll
    for (int m = 0; m < 4; ++m)
#pragma unroll
      for (int n = 0; n < 4; ++n)
        acc[m][n] = __builtin_amdgcn_mfma_f32_16x16x32_bf16(af[m], bf[n], acc[m][n], 0, 0, 0);
    __builtin_amdgcn_s_setprio(0);
    if (kt + 1 < NT) {
      if (kt + 2 < NT) asm volatile("s_waitcnt vmcnt(4)" ::: "memory");
      else             asm volatile("s_waitcnt vmcnt(0)" ::: "memory");
      __builtin_amdgcn_s_barrier();
      __builtin_amdgcn_sched_barrier(0);
    }
  }
}

// ---------------- K0: streaming pass: q/k/v/W f32->bf16 + mask bit-pack -------------
// Grid (6144, 5): y=0..2 q/k/v convert, y=3 mask pack, y=4 W convert (x<288).
// Pack layout: chunk c covers mask[c*256..c*256+255];
// bit L of word mwords[c*4+j] = (mask[c*256 + L*4 + j] == 1).
__global__ __launch_bounds__(256) void k_cvt(const float* __restrict__ q,
                                             const float* __restrict__ k,
                                             const float* __restrict__ v,
                                             const float* __restrict__ W,
                                             const int* __restrict__ mask,
                                             unsigned short* __restrict__ qb,
                                             unsigned short* __restrict__ kb,
                                             unsigned short* __restrict__ vb,
                                             unsigned short* __restrict__ Wb,
                                             unsigned long long* __restrict__ mwords) {
  const int y = blockIdx.y;
  if (y == 3) {
    const int nchunks = B_ * S_ * (S_ / 256);  // 131072
    const int lane = threadIdx.x & 63;
    const int wave = (blockIdx.x * 256 + threadIdx.x) >> 6;
    const int nw = gridDim.x * 4;
    int c = wave;
    for (; c + 3 * nw < nchunks; c += 4 * nw) {
      int4 v0 = *reinterpret_cast<const int4*>(&mask[(size_t)c * 256 + lane * 4]);
      int4 v1 = *reinterpret_cast<const int4*>(&mask[(size_t)(c + nw) * 256 + lane * 4]);
      int4 v2 = *reinterpret_cast<const int4*>(&mask[(size_t)(c + 2 * nw) * 256 + lane * 4]);
      int4 v3 = *reinterpret_cast<const int4*>(&mask[(size_t)(c + 3 * nw) * 256 + lane * 4]);
      unsigned long long a0 = __ballot(v0.x == 1), a1 = __ballot(v0.y == 1);
      unsigned long long a2 = __ballot(v0.z == 1), a3 = __ballot(v0.w == 1);
      unsigned long long b0 = __ballot(v1.x == 1), b1 = __ballot(v1.y == 1);
      unsigned long long b2 = __ballot(v1.z == 1), b3 = __ballot(v1.w == 1);
      unsigned long long c0 = __ballot(v2.x == 1), c1 = __ballot(v2.y == 1);
      unsigned long long c2 = __ballot(v2.z == 1), c3 = __ballot(v2.w == 1);
      unsigned long long d0 = __ballot(v3.x == 1), d1 = __ballot(v3.y == 1);
      unsigned long long d2 = __ballot(v3.z == 1), d3 = __ballot(v3.w == 1);
      if (lane == 0) {
        *reinterpret_cast<ulonglong2*>(&mwords[(size_t)c * 4]) = make_ulonglong2(a0, a1);
        *reinterpret_cast<ulonglong2*>(&mwords[(size_t)c * 4 + 2]) = make_ulonglong2(a2, a3);
        *reinterpret_cast<ulonglong2*>(&mwords[(size_t)(c + nw) * 4]) = make_ulonglong2(b0, b1);
        *reinterpret_cast<ulonglong2*>(&mwords[(size_t)(c + nw) * 4 + 2]) = make_ulonglong2(b2, b3);
        *reinterpret_cast<ulonglong2*>(&mwords[(size_t)(c + 2 * nw) * 4]) = make_ulonglong2(c0, c1);
        *reinterpret_cast<ulonglong2*>(&mwords[(size_t)(c + 2 * nw) * 4 + 2]) = make_ulonglong2(c2, c3);
        *reinterpret_cast<ulonglong2*>(&mwords[(size_t)(c + 3 * nw) * 4]) = make_ulonglong2(d0, d1);
        *reinterpret_cast<ulonglong2*>(&mwords[(size_t)(c + 3 * nw) * 4 + 2]) = make_ulonglong2(d2, d3);
      }
    }
    for (; c < nchunks; c += nw) {
      int4 v0 = *reinterpret_cast<const int4*>(&mask[(size_t)c * 256 + lane * 4]);
      unsigned long long a0 = __ballot(v0.x == 1), a1 = __ballot(v0.y == 1);
      unsigned long long a2 = __ballot(v0.z == 1), a3 = __ballot(v0.w == 1);
      if (lane == 0) {
        *reinterpret_cast<ulonglong2*>(&mwords[(size_t)c * 4]) = make_ulonglong2(a0, a1);
        *reinterpret_cast<ulonglong2*>(&mwords[(size_t)c * 4 + 2]) = make_ulonglong2(a2, a3);
      }
    }
    return;
  }
  if (y == 4) {
    if (blockIdx.x < 288) {
      const int i0 = blockIdx.x * 512 + threadIdx.x;
      const float4* s4 = reinterpret_cast<const float4*>(W);
      uint2* d2 = reinterpret_cast<uint2*>(Wb);
      float4 f0 = s4[i0];
      float4 f1 = s4[i0 + 256];
      d2[i0]       = make_uint2(pk2bf(f0.x, f0.y), pk2bf(f0.z, f0.w));
      d2[i0 + 256] = make_uint2(pk2bf(f1.x, f1.y), pk2bf(f1.z, f1.w));
    }
    return;
  }
  const float* src = (y == 0) ? q : (y == 1) ? k : v;
  unsigned short* dst = (y == 0) ? qb : (y == 1) ? kb : vb;
  const int i0 = blockIdx.x * 512 + threadIdx.x;
  const float4* s4 = reinterpret_cast<const float4*>(src);
  uint2* d2 = reinterpret_cast<uint2*>(dst);
  float4 f0 = s4[i0];
  float4 f1 = s4[i0 + 256];
  d2[i0]       = make_uint2(pk2bf(f0.x, f0.y), pk2bf(f0.z, f0.w));
  d2[i0 + 256] = make_uint2(pk2bf(f1.x, f1.y), pk2bf(f1.z, f1.w));
}

// ---------------- K1: projection GEMM  O = Xb @ Wb^T + b  (bf16 in/out) -------------
// 1-D grid 2304; XCD chunk = 288 logical ids = 48 A-panels (each panel 1 XCD).
__global__ __launch_bounds__(256, 3) void k_projb(const unsigned short* __restrict__ Xb,
                                                  const unsigned short* __restrict__ Wb,
                                                  const float* __restrict__ bias,
                                                  unsigned short* __restrict__ qp,
                                                  unsigned short* __restrict__ kp,
                                                  unsigned short* __restrict__ vp) {
  __shared__ __attribute__((aligned(16))) unsigned short As[3 * 4096];  // 24 KB
  __shared__ __attribute__((aligned(16))) unsigned short Bs[3 * 4096];  // 24 KB
  const int tid = threadIdx.x, lane = tid & 63, wid = tid >> 6;
  const int wm = wid >> 1, wn = wid & 1;
  const int id = blockIdx.x;
  const int swz = (id & 7) * 288 + (id >> 3);   // 2304 = 8 * 288
  const int z = swz / 768;
  const int rem = swz - z * 768;
  const int r0 = (rem / 6) * 128, c0 = (rem % 6) * 128;
  const unsigned short* X = Xb + (size_t)z * (B_ * S_ * E_);
  unsigned short* O = (z == 0) ? qp : ((z == 1) ? kp : vp);

  f32x4 acc[4][4] = {};
  gemm128((const char*)(X + (size_t)r0 * E_), (const char*)(Wb + (size_t)c0 * E_),
          E_ * 2, E_ * 2, E_ / 32, As, Bs, tid, wm, wn, lane, acc);

  float bcol[4];
#pragma unroll
  for (int n = 0; n < 4; ++n) bcol[n] = bias[c0 + wn * 64 + n * 16 + (lane & 15)];
#pragma unroll
  for (int m = 0; m < 4; ++m)
#pragma unroll
    for (int r = 0; r < 4; ++r) {
      const int row = r0 + wm * 64 + m * 16 + (lane >> 4) * 4 + r;
#pragma unroll
      for (int n = 0; n < 4; ++n) {
        const int col = c0 + wn * 64 + n * 16 + (lane & 15);
        O[(size_t)row * E_ + col] = (unsigned short)pk2bf(acc[m][n][r] + bcol[n], 0.f);
      }
    }
}

// ---------------- K2: scores GEMM + mask + exp + rowsum + (v-transpose rideshare) ---
// Grid 5120 = 3072 vtrans blocks (first) + 2048 scores blocks (3072%8==0: XCD ok).
// scores XCD chunk = 256 logical ids = one batch (qp[b]+kp[b] = 6 MB, L2-fits).
__global__ __launch_bounds__(256, 3) void k_scores(const unsigned short* __restrict__ qp,
                                                   const unsigned short* __restrict__ kp,
                                                   const unsigned long long* __restrict__ mwords,
                                                   unsigned short* __restrict__ P,
                                                   float* __restrict__ rowsum,
                                                   const unsigned short* __restrict__ vp,
                                                   unsigned short* __restrict__ vpT) {
  __shared__ __attribute__((aligned(16))) unsigned short SM[25088];  // 49 KB arena
  unsigned short* As = SM;
  unsigned short* Bs = SM + 12288;
  float* rlds = (float*)(SM + 24576);
  const int tid = threadIdx.x, lane = tid & 63, wid = tid >> 6;
  if (blockIdx.x < 3072) {
    // ---- v-transpose path: vp [B*S][E] -> vpT [B][E][S] ----
    unsigned short (*t)[72] = (unsigned short (*)[72])SM;
    const int id = blockIdx.x;
    const int st = id & 31;
    const int ot = (id >> 5) % 12;
    const int b = id / 384;
#pragma unroll
    for (int i = 0; i < 2; ++i) {
      int f = i * 256 + tid;
      int s = f >> 3, c8 = f & 7;
      uint4 vv = *reinterpret_cast<const uint4*>(
          &vp[((size_t)b * S_ + st * 64 + s) * E_ + ot * 64 + c8 * 8]);
      *reinterpret_cast<uint4*>(&t[s][c8 * 8]) = vv;
    }
    __syncthreads();
    const int o = tid >> 2;
    const int sb = (tid & 3) * 16;
    unsigned p[8];
#pragma unroll
    for (int j = 0; j < 8; ++j)
      p[j] = (unsigned)t[sb + 2 * j][o] | ((unsigned)t[sb + 2 * j + 1][o] << 16);
    uint4 w0 = make_uint4(p[0], p[1], p[2], p[3]);
    uint4 w1 = make_uint4(p[4], p[5], p[6], p[7]);
    size_t ob = ((size_t)b * E_ + ot * 64 + o) * S_ + st * 64 + sb;
    *reinterpret_cast<uint4*>(&vpT[ob]) = w0;
    *reinterpret_cast<uint4*>(&vpT[ob + 8]) = w1;
    return;
  }
  // ---- scores GEMM path ----
  const int wm = wid >> 1, wn = wid & 1;
  const int id = blockIdx.x - 3072;
  const int swz = (id & 7) * 256 + (id >> 3);   // 2048 = 8 * 256
  const int b = swz >> 8;
  const int qt = (swz >> 4) & 15, yt = swz & 15;
  f32x4 acc[4][4] = {};
  gemm128((const char*)(qp + ((size_t)b * S_ + qt * 128) * E_),
          (const char*)(kp + ((size_t)b * S_ + yt * 128) * E_),
          E_ * 2, E_ * 2, E_ / 32, As, Bs, tid, wm, wn, lane, acc);

  const float SC = (float)(1.4426950408889634 / 27.712812921102035);  // log2(e)/sqrt(768)
#pragma unroll
  for (int m = 0; m < 4; ++m)
#pragma unroll
    for (int r = 0; r < 4; ++r) {
      const int rloc = wm * 64 + m * 16 + (lane >> 4) * 4 + r;
      const int grow = qt * 128 + rloc;
      const size_t rowoff = ((size_t)b * S_ + grow) * S_;
      // chunk = yt>>1 (256 cols); word j = lane&3; bit L = (yt&1)*32 + wn*16 + n*4 + (l15>>2)
      const unsigned long long mw =
          mwords[(((size_t)b * S_ + grow) * 8 + (yt >> 1)) * 4 + (lane & 3)];
      const int shb = (yt & 1) * 32 + wn * 16 + ((lane & 15) >> 2);
      const int cbase = yt * 128 + wn * 64 + (lane & 15);
      float radd = 0.f;
#pragma unroll
      for (int n = 0; n < 4; ++n) {
        float pv = ((mw >> (shb + n * 4)) & 1ull)
                       ? 0.f
                       : __builtin_amdgcn_exp2f(acc[m][n][r] * SC);
        radd += pv;
        P[rowoff + cbase + n * 16] = (unsigned short)pk2bf(pv, 0.f);
      }
      float vsum = radd;
      vsum += __shfl_xor(vsum, 1);
      vsum += __shfl_xor(vsum, 2);
      vsum += __shfl_xor(vsum, 4);
      vsum += __shfl_xor(vsum, 8);
      if ((lane & 15) == 0) rlds[rloc * 2 + wn] = vsum;
    }
  __syncthreads();
  if (tid < 128) {
    rowsum[(size_t)yt * (B_ * S_) + (size_t)b * S_ + qt * 128 + tid] =
        rlds[tid * 2] + rlds[tid * 2 + 1];
  }
}

// ---------------- K2b: inv_rs = 1 / sum_yt rowsum -----------------------------------
__global__ __launch_bounds__(256) void k_invrs(const float* __restrict__ rowsum,
                                               float* __restrict__ inv_rs) {
  int i = blockIdx.x * 256 + threadIdx.x;
  float t = 0.f;
#pragma unroll
  for (int g = 0; g < 16; ++g) t += rowsum[(size_t)g * (B_ * S_) + i];
  inv_rs[i] = 1.0f / t;
}

// ---------------- K3: out = (P @ vpT^T) * inv_rs  (f32 out) -------------------------
// 1-D grid 768; XCD chunk = 96 logical ids = exactly one batch.
__global__ __launch_bounds__(256, 3) void k_pv(const unsigned short* __restrict__ P,
                                               const unsigned short* __restrict__ vpT,
                                               const float* __restrict__ inv_rs,
                                               float* __restrict__ out) {
  __shared__ __attribute__((aligned(16))) unsigned short As[3 * 4096];
  __shared__ __attribute__((aligned(16))) unsigned short Bs[3 * 4096];
  const int tid = threadIdx.x, lane = tid & 63, wid = tid >> 6;
  const int wm = wid >> 1, wn = wid & 1;
  const int id = blockIdx.x;
  const int swz = (id & 7) * 96 + (id >> 3);    // 768 = 8 * 96
  const int b = swz / 96;
  const int rem = swz - b * 96;
  const int mt = rem / 6, et = rem % 6;
  f32x4 acc[4][4] = {};
  gemm128((const char*)(P + ((size_t)b * S_ + mt * 128) * S_),
          (const char*)(vpT + ((size_t)b * E_ + et * 128) * S_),
          S_ * 2, S_ * 2, S_ / 32, As, Bs, tid, wm, wn, lane, acc);

#pragma unroll
  for (int m = 0; m < 4; ++m)
#pragma unroll
    for (int r = 0; r < 4; ++r) {
      const int grow = mt * 128 + wm * 64 + m * 16 + (lane >> 4) * 4 + r;
      const float inv = inv_rs[b * S_ + grow];
#pragma unroll
      for (int n = 0; n < 4; ++n) {
        const int col = et * 128 + wn * 64 + n * 16 + (lane & 15);
        out[((size_t)b * S_ + grow) * E_ + col] = acc[m][n][r] * inv;
      }
    }
}

extern "C" void kernel_launch(void* const* d_in, const int* in_sizes, int n_in,
                              void* d_out, int out_size, void* d_ws, size_t ws_size,
                              hipStream_t stream) {
  const float* q = (const float*)d_in[0];
  const float* k = (const float*)d_in[1];
  const float* v = (const float*)d_in[2];
  const int* mask = (const int*)d_in[3];
  const float* W = (const float*)d_in[4];
  const float* bias = (const float*)d_in[5];
  float* out = (float*)d_out;
  char* ws = (char*)d_ws;

  // workspace layout (bytes); high-water ~145 MB
  unsigned short* qb = (unsigned short*)(ws + 0);          // 3x24MB, contiguous q,k,v
  unsigned short* kb = (unsigned short*)(ws + 25165824);
  unsigned short* vb = (unsigned short*)(ws + 50331648);
  unsigned short* Wb = (unsigned short*)(ws + 75497472);   // 1.18 MB, dead after k_projb
  unsigned short* qp = (unsigned short*)(ws + 76677120);   // 24 MB
  unsigned short* kp = (unsigned short*)(ws + 101842944);  // 24 MB
  unsigned short* vpT = (unsigned short*)(ws + 127008768); // 24 MB
  // aliases over dead regions:
  unsigned short* P = (unsigned short*)(ws + 0);           // 64 MiB over dead qb/kb/vb
  float* rowsum = (float*)(ws + 75497472);                 // 1 MB over dead Wb
  float* inv_rs = (float*)(ws + 76546048);                 // 64 KB, inside Wb slot
  unsigned short* vp_tmp = (unsigned short*)d_out;         // 24 MB scratch; k_pv overwrites
  unsigned long long* mwords =
      (unsigned long long*)((char*)d_out + 25165824);      // 4 MB in d_out; dead before k_pv
  (void)in_sizes; (void)n_in; (void)out_size; (void)ws_size;

  dim3 blk(256, 1, 1);
  k_cvt<<<dim3(6144, 5, 1), blk, 0, stream>>>(q, k, v, W, mask, qb, kb, vb, Wb, mwords);
  k_projb<<<dim3(2304, 1, 1), blk, 0, stream>>>(qb, Wb, bias, qp, kp, vp_tmp);
  k_scores<<<dim3(5120, 1, 1), blk, 0, stream>>>(qp, kp, mwords, P, rowsum, vp_tmp, vpT);
  k_invrs<<<dim3(64, 1, 1), blk, 0, stream>>>(rowsum, inv_rs);
  k_pv<<<dim3(768, 1, 1), blk, 0, stream>>>(P, vpT, inv_rs, out);
}

// Round 13
// 286.861 us; speedup vs baseline: 1.0589x; 1.0589x over previous
//
#include <hip/hip_runtime.h>
#include <hip/hip_bf16.h>
#include <stdint.h>

#define B_ 8
#define S_ 2048
#define E_ 768

typedef __attribute__((ext_vector_type(4))) float f32x4;
typedef __attribute__((ext_vector_type(8))) short bf16x8;

// GEMM core (best-known, r10/r11): BM=BN=128, BK=32, 256 thr (4 waves 2Mx2N),
// 2 LDS buffers x (A 8KB + B 8KB) = 32 KB -> 4-5 blocks/CU resident.
// 1-D grids, XCD-chunked (T1; bijective, grids %8==0).

__device__ __forceinline__ unsigned pk2bf(float x, float y) {
  unsigned r;
  asm("v_cvt_pk_bf16_f32 %0, %1, %2" : "=v"(r) : "v"(x), "v"(y));
  return r;
}

__device__ __forceinline__ void gll16(const void* g, void* l) {
  __builtin_amdgcn_global_load_lds((const __attribute__((address_space(1))) void*)g,
                                   (__attribute__((address_space(3))) void*)l, 16, 0, 0);
}

// Swizzle (64B rows = 32 bf16): chunk' = chunk ^ ((row>>1)&3) -> 2-way (free).
// LDS dest linear; global SOURCE pre-swizzled (involution, rule #21).
__device__ __forceinline__ void gemm128(const char* __restrict__ Ab,
                                        const char* __restrict__ Bb,
                                        int ldA, int ldB, int NT,
                                        unsigned short* As, unsigned short* Bs,
                                        int tid, int wm, int wn, int lane,
                                        f32x4 (&acc)[4][4]) {
  unsigned sA[2], sB[2], lin2[2];
#pragma unroll
  for (int i = 0; i < 2; ++i) {
    const unsigned lin = (unsigned)i * 4096u + (unsigned)tid * 16u;
    const unsigned row = lin >> 6, ch = (lin >> 4) & 3u;
    const unsigned sw = (ch ^ ((row >> 1) & 3u)) << 4;
    sA[i] = row * (unsigned)ldA + sw;
    sB[i] = row * (unsigned)ldB + sw;
    lin2[i] = lin;
  }
  unsigned aoff[4], boff[4];
#pragma unroll
  for (int m = 0; m < 4; ++m) {
    unsigned row = (unsigned)(wm * 64 + m * 16 + (lane & 15));
    aoff[m] = row * 64 + ((((unsigned)lane >> 4) ^ ((row >> 1) & 3u)) << 4);
    row = (unsigned)(wn * 64 + m * 16 + (lane & 15));
    boff[m] = row * 64 + ((((unsigned)lane >> 4) ^ ((row >> 1) & 3u)) << 4);
  }
#pragma unroll
  for (int i = 0; i < 2; ++i) {
    gll16(Ab + sA[i], (char*)As + lin2[i]);
    gll16(Bb + sB[i], (char*)Bs + lin2[i]);
  }
  asm volatile("s_waitcnt vmcnt(0)" ::: "memory");
  __builtin_amdgcn_s_barrier();
  __builtin_amdgcn_sched_barrier(0);
  for (int kt = 0; kt < NT; ++kt) {
    const char* Ac = (const char*)As + (kt & 1) * 8192;
    const char* Bc = (const char*)Bs + (kt & 1) * 8192;
    char* An = (char*)As + ((kt + 1) & 1) * 8192;
    char* Bn = (char*)Bs + ((kt + 1) & 1) * 8192;
    if (kt + 1 < NT) {
      const size_t ko = (size_t)(kt + 1) * 64;
#pragma unroll
      for (int i = 0; i < 2; ++i) {
        gll16(Ab + sA[i] + ko, An + lin2[i]);
        gll16(Bb + sB[i] + ko, Bn + lin2[i]);
      }
    }
    bf16x8 af[4], bf[4];
#pragma unroll
    for (int m = 0; m < 4; ++m) af[m] = *reinterpret_cast<const bf16x8*>(Ac + aoff[m]);
#pragma unroll
    for (int n = 0; n < 4; ++n) bf[n] = *reinterpret_cast<const bf16x8*>(Bc + boff[n]);
    asm volatile("s_waitcnt lgkmcnt(0)" ::: "memory");
    __builtin_amdgcn_sched_barrier(0);
    __builtin_amdgcn_s_setprio(1);
#pragma unroll
    for (int m = 0; m < 4; ++m)
#pragma unroll
      for (int n = 0; n < 4; ++n)
        acc[m][n] = __builtin_amdgcn_mfma_f32_16x16x32_bf16(af[m], bf[n], acc[m][n], 0, 0, 0);
    __builtin_amdgcn_s_setprio(0);
    if (kt + 1 < NT) {
      asm volatile("s_waitcnt vmcnt(0)" ::: "memory");
      __builtin_amdgcn_s_barrier();
      __builtin_amdgcn_sched_barrier(0);
    }
  }
}

// ---------------- K0: streaming pass: q/k/v/W f32->bf16 + mask bit-pack -------------
// Grid (6144, 5): y=0..2 q/k/v convert, y=3 mask pack, y=4 W convert (x<288).
// Pack layout: chunk c covers mask[c*256..c*256+255];
// bit L of word mwords[c*4+j] = (mask[c*256 + L*4 + j] == 1).
__global__ __launch_bounds__(256) void k_cvt(const float* __restrict__ q,
                                             const float* __restrict__ k,
                                             const float* __restrict__ v,
                                             const float* __restrict__ W,
                                             const int* __restrict__ mask,
                                             unsigned short* __restrict__ qb,
                                             unsigned short* __restrict__ kb,
                                             unsigned short* __restrict__ vb,
                                             unsigned short* __restrict__ Wb,
                                             unsigned long long* __restrict__ mwords) {
  const int y = blockIdx.y;
  if (y == 3) {
    const int nchunks = B_ * S_ * (S_ / 256);  // 131072
    const int lane = threadIdx.x & 63;
    const int wave = (blockIdx.x * 256 + threadIdx.x) >> 6;
    const int nw = gridDim.x * 4;
    int c = wave;
    for (; c + 3 * nw < nchunks; c += 4 * nw) {
      int4 v0 = *reinterpret_cast<const int4*>(&mask[(size_t)c * 256 + lane * 4]);
      int4 v1 = *reinterpret_cast<const int4*>(&mask[(size_t)(c + nw) * 256 + lane * 4]);
      int4 v2 = *reinterpret_cast<const int4*>(&mask[(size_t)(c + 2 * nw) * 256 + lane * 4]);
      int4 v3 = *reinterpret_cast<const int4*>(&mask[(size_t)(c + 3 * nw) * 256 + lane * 4]);
      unsigned long long a0 = __ballot(v0.x == 1), a1 = __ballot(v0.y == 1);
      unsigned long long a2 = __ballot(v0.z == 1), a3 = __ballot(v0.w == 1);
      unsigned long long b0 = __ballot(v1.x == 1), b1 = __ballot(v1.y == 1);
      unsigned long long b2 = __ballot(v1.z == 1), b3 = __ballot(v1.w == 1);
      unsigned long long c0 = __ballot(v2.x == 1), c1 = __ballot(v2.y == 1);
      unsigned long long c2 = __ballot(v2.z == 1), c3 = __ballot(v2.w == 1);
      unsigned long long d0 = __ballot(v3.x == 1), d1 = __ballot(v3.y == 1);
      unsigned long long d2 = __ballot(v3.z == 1), d3 = __ballot(v3.w == 1);
      if (lane == 0) {
        *reinterpret_cast<ulonglong2*>(&mwords[(size_t)c * 4]) = make_ulonglong2(a0, a1);
        *reinterpret_cast<ulonglong2*>(&mwords[(size_t)c * 4 + 2]) = make_ulonglong2(a2, a3);
        *reinterpret_cast<ulonglong2*>(&mwords[(size_t)(c + nw) * 4]) = make_ulonglong2(b0, b1);
        *reinterpret_cast<ulonglong2*>(&mwords[(size_t)(c + nw) * 4 + 2]) = make_ulonglong2(b2, b3);
        *reinterpret_cast<ulonglong2*>(&mwords[(size_t)(c + 2 * nw) * 4]) = make_ulonglong2(c0, c1);
        *reinterpret_cast<ulonglong2*>(&mwords[(size_t)(c + 2 * nw) * 4 + 2]) = make_ulonglong2(c2, c3);
        *reinterpret_cast<ulonglong2*>(&mwords[(size_t)(c + 3 * nw) * 4]) = make_ulonglong2(d0, d1);
        *reinterpret_cast<ulonglong2*>(&mwords[(size_t)(c + 3 * nw) * 4 + 2]) = make_ulonglong2(d2, d3);
      }
    }
    for (; c < nchunks; c += nw) {
      int4 v0 = *reinterpret_cast<const int4*>(&mask[(size_t)c * 256 + lane * 4]);
      unsigned long long a0 = __ballot(v0.x == 1), a1 = __ballot(v0.y == 1);
      unsigned long long a2 = __ballot(v0.z == 1), a3 = __ballot(v0.w == 1);
      if (lane == 0) {
        *reinterpret_cast<ulonglong2*>(&mwords[(size_t)c * 4]) = make_ulonglong2(a0, a1);
        *reinterpret_cast<ulonglong2*>(&mwords[(size_t)c * 4 + 2]) = make_ulonglong2(a2, a3);
      }
    }
    return;
  }
  if (y == 4) {
    if (blockIdx.x < 288) {
      const int i0 = blockIdx.x * 512 + threadIdx.x;
      const float4* s4 = reinterpret_cast<const float4*>(W);
      uint2* d2 = reinterpret_cast<uint2*>(Wb);
      float4 f0 = s4[i0];
      float4 f1 = s4[i0 + 256];
      d2[i0]       = make_uint2(pk2bf(f0.x, f0.y), pk2bf(f0.z, f0.w));
      d2[i0 + 256] = make_uint2(pk2bf(f1.x, f1.y), pk2bf(f1.z, f1.w));
    }
    return;
  }
  const float* src = (y == 0) ? q : (y == 1) ? k : v;
  unsigned short* dst = (y == 0) ? qb : (y == 1) ? kb : vb;
  const int i0 = blockIdx.x * 512 + threadIdx.x;
  const float4* s4 = reinterpret_cast<const float4*>(src);
  uint2* d2 = reinterpret_cast<uint2*>(dst);
  float4 f0 = s4[i0];
  float4 f1 = s4[i0 + 256];
  d2[i0]       = make_uint2(pk2bf(f0.x, f0.y), pk2bf(f0.z, f0.w));
  d2[i0 + 256] = make_uint2(pk2bf(f1.x, f1.y), pk2bf(f1.z, f1.w));
}

// ---------------- K1: projection GEMM  O = Xb @ Wb^T + b  (bf16 in/out) -------------
// 1-D grid 2304; XCD chunk = 288 logical ids = 48 A-panels.
// z==2 (vp) blocks write TRANSPOSED to vpT[B][E][S] via the retired LDS arena.
__global__ __launch_bounds__(256, 4) void k_projb(const unsigned short* __restrict__ Xb,
                                                  const unsigned short* __restrict__ Wb,
                                                  const float* __restrict__ bias,
                                                  unsigned short* __restrict__ qp,
                                                  unsigned short* __restrict__ kp,
                                                  unsigned short* __restrict__ vpT) {
  __shared__ __attribute__((aligned(16))) unsigned short SM[16896];  // 33 KB arena
  unsigned short* As = SM;
  unsigned short* Bs = SM + 8192;
  const int tid = threadIdx.x, lane = tid & 63, wid = tid >> 6;
  const int wm = wid >> 1, wn = wid & 1;
  const int id = blockIdx.x;
  const int swz = (id & 7) * 288 + (id >> 3);   // 2304 = 8 * 288
  const int z = swz / 768;
  const int rem = swz - z * 768;
  const int r0 = (rem / 6) * 128, c0 = (rem % 6) * 128;
  const unsigned short* X = Xb + (size_t)z * (B_ * S_ * E_);

  f32x4 acc[4][4] = {};
  gemm128((const char*)(X + (size_t)r0 * E_), (const char*)(Wb + (size_t)c0 * E_),
          E_ * 2, E_ * 2, E_ / 32, As, Bs, tid, wm, wn, lane, acc);

  float bcol[4];
#pragma unroll
  for (int n = 0; n < 4; ++n) bcol[n] = bias[c0 + wn * 64 + n * 16 + (lane & 15)];

  if (z == 2) {
    // transpose tile through LDS (stride 132 ushorts -> ~2-4 way, free-ish)
    __syncthreads();  // all waves done with As/Bs reads
#pragma unroll
    for (int m = 0; m < 4; ++m)
#pragma unroll
      for (int r = 0; r < 4; ++r) {
        const int row = wm * 64 + m * 16 + (lane >> 4) * 4 + r;  // s-local
#pragma unroll
        for (int n = 0; n < 4; ++n) {
          const int col = wn * 64 + n * 16 + (lane & 15);        // e-local
          SM[col * 132 + row] = (unsigned short)pk2bf(acc[m][n][r] + bcol[n], 0.f);
        }
      }
    __syncthreads();
    const int b = r0 >> 11;         // r0 / 2048 (tile never straddles batches)
    const int s0 = r0 & 2047;
#pragma unroll
    for (int i = 0; i < 16; ++i) {
      const int f = i * 256 + tid;  // 4096 uint2 total
      const int e = f >> 5, su = f & 31;
      uint2 val = *reinterpret_cast<const uint2*>(&SM[e * 132 + su * 4]);
      *reinterpret_cast<uint2*>(&vpT[((size_t)b * E_ + c0 + e) * S_ + s0 + su * 4]) = val;
    }
    return;
  }

  unsigned short* O = (z == 0) ? qp : kp;
#pragma unroll
  for (int m = 0; m < 4; ++m)
#pragma unroll
    for (int r = 0; r < 4; ++r) {
      const int row = r0 + wm * 64 + m * 16 + (lane >> 4) * 4 + r;
#pragma unroll
      for (int n = 0; n < 4; ++n) {
        const int col = c0 + wn * 64 + n * 16 + (lane & 15);
        O[(size_t)row * E_ + col] = (unsigned short)pk2bf(acc[m][n][r] + bcol[n], 0.f);
      }
    }
}

// ---------------- K2: scores tile GEMM + mask + exp (unnormalized) + rowsum ---------
// 1-D grid 2048; XCD chunk = 256 logical ids = one batch (qp[b]+kp[b] = 6 MB, L2-fit).
// LDS exactly 32 KB (rlds aliases retired As) -> 5 blocks/CU ceiling.
__global__ __launch_bounds__(256, 4) void k_scores(const unsigned short* __restrict__ qp,
                                                   const unsigned short* __restrict__ kp,
                                                   const unsigned long long* __restrict__ mwords,
                                                   unsigned short* __restrict__ P,
                                                   float* __restrict__ rowsum) {
  __shared__ __attribute__((aligned(16))) unsigned short SM[16384];  // 32 KB exactly
  unsigned short* As = SM;
  unsigned short* Bs = SM + 8192;
  float* rlds = (float*)SM;  // aliases As after the GEMM (barrier below)
  const int tid = threadIdx.x, lane = tid & 63, wid = tid >> 6;
  const int wm = wid >> 1, wn = wid & 1;
  const int id = blockIdx.x;
  const int swz = (id & 7) * 256 + (id >> 3);   // 2048 = 8 * 256
  const int b = swz >> 8;
  const int qt = (swz >> 4) & 15, yt = swz & 15;
  f32x4 acc[4][4] = {};
  gemm128((const char*)(qp + ((size_t)b * S_ + qt * 128) * E_),
          (const char*)(kp + ((size_t)b * S_ + yt * 128) * E_),
          E_ * 2, E_ * 2, E_ / 32, As, Bs, tid, wm, wn, lane, acc);
  __syncthreads();  // retire As/Bs before rlds aliasing writes

  const float SC = (float)(1.4426950408889634 / 27.712812921102035);  // log2(e)/sqrt(768)
#pragma unroll
  for (int m = 0; m < 4; ++m)
#pragma unroll
    for (int r = 0; r < 4; ++r) {
      const int rloc = wm * 64 + m * 16 + (lane >> 4) * 4 + r;
      const int grow = qt * 128 + rloc;
      const size_t rowoff = ((size_t)b * S_ + grow) * S_;
      // chunk = yt>>1 (256 cols); word j = lane&3; bit L = (yt&1)*32 + wn*16 + n*4 + (l15>>2)
      const unsigned long long mw =
          mwords[(((size_t)b * S_ + grow) * 8 + (yt >> 1)) * 4 + (lane & 3)];
      const int shb = (yt & 1) * 32 + wn * 16 + ((lane & 15) >> 2);
      const int cbase = yt * 128 + wn * 64 + (lane & 15);
      float radd = 0.f;
#pragma unroll
      for (int n = 0; n < 4; ++n) {
        float pv = ((mw >> (shb + n * 4)) & 1ull)
                       ? 0.f
                       : __builtin_amdgcn_exp2f(acc[m][n][r] * SC);
        radd += pv;
        P[rowoff + cbase + n * 16] = (unsigned short)pk2bf(pv, 0.f);
      }
      float vsum = radd;
      vsum += __shfl_xor(vsum, 1);
      vsum += __shfl_xor(vsum, 2);
      vsum += __shfl_xor(vsum, 4);
      vsum += __shfl_xor(vsum, 8);
      if ((lane & 15) == 0) rlds[rloc * 2 + wn] = vsum;
    }
  __syncthreads();
  if (tid < 128) {
    rowsum[(size_t)yt * (B_ * S_) + (size_t)b * S_ + qt * 128 + tid] =
        rlds[tid * 2] + rlds[tid * 2 + 1];
  }
}

// ---------------- K2b: inv_rs = 1 / sum_yt rowsum -----------------------------------
__global__ __launch_bounds__(256) void k_invrs(const float* __restrict__ rowsum,
                                               float* __restrict__ inv_rs) {
  int i = blockIdx.x * 256 + threadIdx.x;
  float t = 0.f;
#pragma unroll
  for (int g = 0; g < 16; ++g) t += rowsum[(size_t)g * (B_ * S_) + i];
  inv_rs[i] = 1.0f / t;
}

// ---------------- K3: out = (P @ vpT^T) * inv_rs  (f32 out) -------------------------
// 1-D grid 768; XCD chunk = 96 logical ids = exactly one batch.
__global__ __launch_bounds__(256, 4) void k_pv(const unsigned short* __restrict__ P,
                                               const unsigned short* __restrict__ vpT,
                                               const float* __restrict__ inv_rs,
                                               float* __restrict__ out) {
  __shared__ __attribute__((aligned(16))) unsigned short SM[16384];  // 32 KB
  unsigned short* As = SM;
  unsigned short* Bs = SM + 8192;
  const int tid = threadIdx.x, lane = tid & 63, wid = tid >> 6;
  const int wm = wid >> 1, wn = wid & 1;
  const int id = blockIdx.x;
  const int swz = (id & 7) * 96 + (id >> 3);    // 768 = 8 * 96
  const int b = swz / 96;
  const int rem = swz - b * 96;
  const int mt = rem / 6, et = rem % 6;
  f32x4 acc[4][4] = {};
  gemm128((const char*)(P + ((size_t)b * S_ + mt * 128) * S_),
          (const char*)(vpT + ((size_t)b * E_ + et * 128) * S_),
          S_ * 2, S_ * 2, S_ / 32, As, Bs, tid, wm, wn, lane, acc);

#pragma unroll
  for (int m = 0; m < 4; ++m)
#pragma unroll
    for (int r = 0; r < 4; ++r) {
      const int grow = mt * 128 + wm * 64 + m * 16 + (lane >> 4) * 4 + r;
      const float inv = inv_rs[b * S_ + grow];
#pragma unroll
      for (int n = 0; n < 4; ++n) {
        const int col = et * 128 + wn * 64 + n * 16 + (lane & 15);
        out[((size_t)b * S_ + grow) * E_ + col] = acc[m][n][r] * inv;
      }
    }
}

extern "C" void kernel_launch(void* const* d_in, const int* in_sizes, int n_in,
                              void* d_out, int out_size, void* d_ws, size_t ws_size,
                              hipStream_t stream) {
  const float* q = (const float*)d_in[0];
  const float* k = (const float*)d_in[1];
  const float* v = (const float*)d_in[2];
  const int* mask = (const int*)d_in[3];
  const float* W = (const float*)d_in[4];
  const float* bias = (const float*)d_in[5];
  float* out = (float*)d_out;
  char* ws = (char*)d_ws;

  // workspace layout (bytes); high-water ~145 MB
  unsigned short* qb = (unsigned short*)(ws + 0);          // 3x24MB, contiguous q,k,v
  unsigned short* kb = (unsigned short*)(ws + 25165824);
  unsigned short* vb = (unsigned short*)(ws + 50331648);
  unsigned short* Wb = (unsigned short*)(ws + 75497472);   // 1.18 MB, dead after k_projb
  unsigned short* qp = (unsigned short*)(ws + 76677120);   // 24 MB
  unsigned short* kp = (unsigned short*)(ws + 101842944);  // 24 MB
  unsigned short* vpT = (unsigned short*)(ws + 127008768); // 24 MB (written by k_projb z==2)
  // aliases over dead regions:
  unsigned short* P = (unsigned short*)(ws + 0);           // 64 MiB over dead qb/kb/vb
  float* rowsum = (float*)(ws + 75497472);                 // 1 MB over dead Wb
  float* inv_rs = (float*)(ws + 76546048);                 // 64 KB, inside Wb slot
  unsigned long long* mwords =
      (unsigned long long*)((char*)d_out + 25165824);      // 4 MB in d_out; dead before k_pv
  (void)in_sizes; (void)n_in; (void)out_size; (void)ws_size;

  dim3 blk(256, 1, 1);
  k_cvt<<<dim3(6144, 5, 1), blk, 0, stream>>>(q, k, v, W, mask, qb, kb, vb, Wb, mwords);
  k_projb<<<dim3(2304, 1, 1), blk, 0, stream>>>(qb, Wb, bias, qp, kp, vpT);
  k_scores<<<dim3(2048, 1, 1), blk, 0, stream>>>(qp, kp, mwords, P, rowsum);
  k_invrs<<<dim3(64, 1, 1), blk, 0, stream>>>(rowsum, inv_rs);
  k_pv<<<dim3(768, 1, 1), blk, 0, stream>>>(P, vpT, inv_rs, out);
}